// Round 1
// 330.692 us; speedup vs baseline: 1.0828x; 1.0828x over previous
//
#include <hip/hip_runtime.h>

typedef unsigned int u32;
typedef unsigned short u16;
typedef __attribute__((ext_vector_type(8))) short bf16x8;
typedef __attribute__((ext_vector_type(4))) float f32x4;

#define B_   512
#define L_   201
#define T_   200
#define H_   128
#define V_   100001
#define G3_  384
#define M_   (B_*T_)         // 102400
#define GPB  16              // batches per k_gi block tile
#define RB   8               // batches per recurrence block
#define NBLK8 (B_/RB)        // 64 recurrence blocks
#define HS   136             // LDS row stride in u16 (>=128!), 272B, 16B-aligned

// ws layout (bytes):
//   [0,256) flag | [256,+25.6MB) embT | [25600768,+78.6MB) gi2 | [104243968,+26.2MB) hseq2
// gi2 (u32, pair-packed, prescaled): per (grp8,t) 1536 u32:
//   gi2[(grp*T+t)*1536 + p*384 + g*128 + i] = pack_bf16(val[b=2p], val[b=2p+1])
//   where val = S_g * (x@Wih^T + bih (+bhh for g<2)), S_rz=-log2e, S_n=+2log2e
// hseq2 (u32, pair-packed): hseq2[(grp*T+t)*512 + p*128 + i] = pack(h[2p][i], h[2p+1][i])
#define OFF_EMBT 256
#define OFF_GI   25600768ull
#define OFF_HSEQ 104243968ull

#define S_RZ (-1.44269504088896340736f)
#define S_N  ( 2.88539008177792681472f)

__device__ __forceinline__ float bf2f(u16 a) {
    return __uint_as_float(((u32)a) << 16);
}
__device__ __forceinline__ void bf2x2(u32 p, float& lo, float& hi) {
    lo = __uint_as_float(p << 16);
    hi = __uint_as_float(p & 0xffff0000u);
}
__device__ __forceinline__ u16 f2bf(float f) {
    u32 u = __float_as_uint(f);
    u32 lsb = (u >> 16) & 1u;
    u += 0x7fffu + lsb;   // RNE
    return (u16)(u >> 16);
}
__device__ __forceinline__ u32 packbf(float a, float b) {
#if __has_builtin(__builtin_amdgcn_cvt_pk_bf16_f32)
    typedef __attribute__((ext_vector_type(2))) __bf16 bf16x2_t;
    bf16x2_t r = __builtin_amdgcn_cvt_pk_bf16_f32(a, b);
    return *(u32*)&r;
#else
    return (u32)f2bf(a) | ((u32)f2bf(b) << 16);
#endif
}
__device__ __forceinline__ float frcp(float x) {
    return __builtin_amdgcn_rcpf(x);
}
__device__ __forceinline__ float fexp2(float x) {
#if __has_builtin(__builtin_amdgcn_exp2f)
    return __builtin_amdgcn_exp2f(x);
#else
    return exp2f(x);
#endif
}
__device__ __forceinline__ void halfred2(float& a, float& b) {
    #pragma unroll
    for (int o = 1; o <= 16; o <<= 1) {
        a += __shfl_xor(a, o, 64);
        b += __shfl_xor(b, o, 64);
    }
}
__device__ __forceinline__ float ldv(const void* p, int dt, int i) {
    return dt ? ((const float*)p)[i] : bf2f(((const u16*)p)[i]);
}
// LDS-only barrier: waits ds ops but does NOT drain vmcnt.
__device__ __forceinline__ void ldsbar() {
    asm volatile("s_waitcnt lgkmcnt(0)\n\ts_barrier" ::: "memory");
}
__device__ __forceinline__ bf16x8 load_frag(const void* W, int dt, int row, int koff) {
    union { bf16x8 v; u32 uu[4]; uint4 q; } r;
    if (dt) {
        const float4* p = (const float4*)((const float*)W + (size_t)row * H_ + koff);
        const float4 a = p[0], b = p[1];
        r.uu[0] = packbf(a.x, a.y); r.uu[1] = packbf(a.z, a.w);
        r.uu[2] = packbf(b.x, b.y); r.uu[3] = packbf(b.z, b.w);
    } else {
        r.q = *(const uint4*)((const u16*)W + (size_t)row * H_ + koff);
    }
    return r.v;
}
#define MFMA16(a, b, c) __builtin_amdgcn_mfma_f32_16x16x32_bf16((a), (b), (c), 0, 0, 0)

// ---------------- K0: dtype sniffer --------------------------------------------
__global__ __launch_bounds__(64) void k_sniff(const u32* __restrict__ raw,
                                              int* __restrict__ flag) {
    const int lane = threadIdx.x;
    int big = 0;
    #pragma unroll
    for (int i = 0; i < 16; i++) {
        const u32 w = raw[lane * 16 + i];
        float lo, hi; bf2x2(w, lo, hi);
        if (!(fabsf(lo) <= 16.0f)) big++;
        if (!(fabsf(hi) <= 16.0f)) big++;
    }
    #pragma unroll
    for (int o = 32; o >= 1; o <<= 1) big += __shfl_xor(big, o, 64);
    if (lane == 0) *flag = (big > 8) ? 1 : 0;
}

// ---------------- K1: transpose emb_W (H,V) -> embT (V,H) bf16 ------------------
__global__ __launch_bounds__(1024) void k_transpose(const void* __restrict__ embW,
                                                    u16* __restrict__ embT,
                                                    const int* __restrict__ flag) {
    const int dt = *flag;
    __shared__ u16 tile[32][33];
    const int v0 = blockIdx.x * 32;
    const int h0 = blockIdx.y * 32;
    const int tx = threadIdx.x, ty = threadIdx.y;
    const int v = v0 + tx, h = h0 + ty;
    if (v < V_) {
        u16 val;
        if (dt) val = f2bf(((const float*)embW)[(size_t)h * V_ + v]);
        else    val = ((const u16*)embW)[(size_t)h * V_ + v];
        tile[ty][tx] = val;
    }
    __syncthreads();
    const int vo = v0 + ty, ho = h0 + tx;
    if (vo < V_) embT[(size_t)vo * H_ + ho] = tile[tx][ty];
}

// ---------------- K2: k_gi — gather + LN1 + gi = x @ Wih^T, transposed MFMA -----
// 1600 blocks x 256 threads (4 waves). Block tile = 16 batches x 4 timesteps.
// Transposed MFMA (A=x, B=Wih): C rows = batches, C cols = out. Output is
// prescaled into exp2 domain and pair-packed for k_rec's 8-batch groups.
__global__ __launch_bounds__(256) void k_gi(const int* __restrict__ seqs,
                                            const u16* __restrict__ embT,
                                            const void* __restrict__ g1,
                                            const void* __restrict__ b1,
                                            const void* __restrict__ Wih,
                                            const void* __restrict__ bih,
                                            const void* __restrict__ bhh,
                                            u32* __restrict__ gi2,
                                            const int* __restrict__ flag) {
    const int dt = *flag;
    __shared__ u16 xs[64 * HS];
    const int tid = threadIdx.x;
    const int w = tid >> 6, L = tid & 63;
    const int q = L >> 4, u = L & 15;
    const int lk = L & 31;
    const int hw = w * 2 + (L >> 5);
    const int grp = blockIdx.x / 50;     // 16-batch group
    const int tc  = blockIdx.x % 50;
    float g1v[4], b1v[4];
    #pragma unroll
    for (int j = 0; j < 4; j++) {
        g1v[j] = ldv(g1, dt, lk * 4 + j);
        b1v[j] = ldv(b1, dt, lk * 4 + j);
    }
    #pragma unroll
    for (int it = 0; it < 8; it++) {
        const int row = hw * 8 + it;
        const int s = row >> 4, bi = row & 15;
        const int b = grp * GPB + bi;
        const int t = tc * 4 + s;
        const int tok = seqs[b * L_ + t];
        const uint2 e = *(const uint2*)&embT[(size_t)tok * H_ + lk * 4];
        float f0, f1, f2, f3; bf2x2(e.x, f0, f1); bf2x2(e.y, f2, f3);
        float s1 = (f0 + f1) + (f2 + f3);
        float s2 = (f0*f0 + f1*f1) + (f2*f2 + f3*f3);
        halfred2(s1, s2);
        const float mu = s1 * (1.0f / H_);
        const float rs = rsqrtf(s2 * (1.0f / H_) - mu * mu + 1e-8f);
        uint2 xw;
        xw.x = packbf((f0-mu)*rs*g1v[0]+b1v[0], (f1-mu)*rs*g1v[1]+b1v[1]);
        xw.y = packbf((f2-mu)*rs*g1v[2]+b1v[2], (f3-mu)*rs*g1v[3]+b1v[3]);
        *(uint2*)&xs[row * HS + lk * 4] = xw;
    }
    // Wih fragments (B operand: col = out = nt*16+u) + scaled biases.
    // bhh for r,z gates folds in here; n-gate bhh stays in k_rec (multiplied by r).
    bf16x8 af[6][4];
    float bS[6], Sj[6];
    #pragma unroll
    for (int j = 0; j < 6; j++) {
        const int nt = w * 6 + j;
        #pragma unroll
        for (int c = 0; c < 4; c++)
            af[j][c] = load_frag(Wih, dt, nt * 16 + u, c * 32 + q * 8);
        const int o = nt * 16 + u;
        const float S = (nt >= 16) ? S_N : S_RZ;
        float bias = ldv(bih, dt, o);
        if (nt < 16) bias += ldv(bhh, dt, o);
        Sj[j] = S; bS[j] = bias * S;
    }
    ldsbar();
    const int rgrp = grp * 2 + (q >> 1);   // 8-batch group
    const int pb = (q & 1) * 2;            // pair base within group
    #pragma unroll
    for (int s = 0; s < 4; s++) {
        bf16x8 xav[4];
        #pragma unroll
        for (int c = 0; c < 4; c++)
            xav[c] = *(const bf16x8*)&xs[(s * 16 + u) * HS + c * 32 + q * 8];
        const int t = tc * 4 + s;
        u32* sb = gi2 + (size_t)(rgrp * T_ + t) * 1536;
        #pragma unroll
        for (int j = 0; j < 6; j++) {
            const int nt = w * 6 + j;
            const int g = nt >> 3;
            const int ih = (nt & 7) * 16 + u;
            f32x4 C = {0.f, 0.f, 0.f, 0.f};
            #pragma unroll
            for (int c = 0; c < 4; c++) C = MFMA16(xav[c], af[j][c], C);
            // C rows = batches 4q+r: pack (4q,4q+1) -> pair pb, (4q+2,4q+3) -> pb+1
            sb[(pb + 0) * 384 + g * 128 + ih] =
                packbf(fmaf(C[0], Sj[j], bS[j]), fmaf(C[1], Sj[j], bS[j]));
            sb[(pb + 1) * 384 + g * 128 + ih] =
                packbf(fmaf(C[2], Sj[j], bS[j]), fmaf(C[3], Sj[j], bS[j]));
        }
    }
}

// ---------------- K3: k_rec — persistent GRU recurrence, 8 batches/block --------
// 64 blocks x 512 threads (8 waves), one per CU. Transposed MFMA: A = h
// (rows = batches, rows 8-15 duplicate 0-7 via ub=u&7), B = Whh^T fragments
// (col = out). C rows = batches -> each lane's 2 valid (batch,hidden) elements
// are a register SELECT (no shuffles). Pointwise: 2 elems/lane (was 4).
__global__ __launch_bounds__(512, 2) void k_rec(const u32* __restrict__ gi2,
                                                const void* __restrict__ Whh,
                                                const void* __restrict__ bhh,
                                                u32* __restrict__ hseq2,
                                                const int* __restrict__ flag) {
    const int dt = *flag;
    __shared__ u16 hbuf[2][RB * HS];
    const int tid = threadIdx.x;
    const int w = tid >> 6, L = tid & 63;
    const int q = L >> 4, u = L & 15;
    const int ub = u & 7;
    const int grp = blockIdx.x;            // 0..63, 8 batches each
    for (int i = tid; i < RB * HS; i += 512) hbuf[0][i] = 0;
    bf16x8 wb[12];
    #pragma unroll
    for (int g = 0; g < 3; g++)
        #pragma unroll
        for (int c = 0; c < 4; c++)
            wb[g * 4 + c] = load_frag(Whh, dt, g * H_ + w * 16 + u, c * 32 + q * 8);
    const float sbn = ldv(bhh, dt, 2 * H_ + w * 16 + u);  // n-gate bias, C-init
    const int p  = ((q & 1) << 1) | (q >> 1);  // pair: batches {2p, 2p+1}
    const int ih = w * 16 + u;                 // this lane's hidden index
    const int hi = q >> 1;                     // take regs {2,3} instead of {0,1}
    const u32* gp = gi2 + (size_t)grp * T_ * 1536 + p * 384 + ih;
    u32* hp = hseq2 + (size_t)grp * T_ * 512 + p * 128 + ih;
    u32 gcur[3], gnxt[3];
    #pragma unroll
    for (int g = 0; g < 3; g++) {
        gcur[g] = gp[g * 128];
        gnxt[g] = gp[1536 + g * 128];
    }
    float hst0 = 0.f, hst1 = 0.f;
    ldsbar();
    #pragma unroll 2
    for (int t = 0; t < T_; t++) {
        const int cur = t & 1;
        const int tpre = (t + 2 < T_) ? (t + 2) : (T_ - 1);
        u32 g2s[3];
        #pragma unroll
        for (int g = 0; g < 3; g++)
            g2s[g] = gp[(size_t)tpre * 1536 + g * 128];
        bf16x8 hbv[4];
        #pragma unroll
        for (int c = 0; c < 4; c++)
            hbv[c] = *(const bf16x8*)&hbuf[cur][ub * HS + c * 32 + q * 8];
        f32x4 ar = {0.f, 0.f, 0.f, 0.f};
        f32x4 az = {0.f, 0.f, 0.f, 0.f};
        f32x4 an = {sbn, sbn, sbn, sbn};
        #pragma unroll
        for (int c = 0; c < 4; c++) ar = MFMA16(hbv[c], wb[c], ar);
        #pragma unroll
        for (int c = 0; c < 4; c++) az = MFMA16(hbv[c], wb[4 + c], az);
        #pragma unroll
        for (int c = 0; c < 4; c++) an = MFMA16(hbv[c], wb[8 + c], an);
        // lane's 2 elements: batches 2p (elem0), 2p+1 (elem1)
        const float grv0 = hi ? ar[2] : ar[0], grv1 = hi ? ar[3] : ar[1];
        const float gzv0 = hi ? az[2] : az[0], gzv1 = hi ? az[3] : az[1];
        const float gnv0 = hi ? an[2] : an[0], gnv1 = hi ? an[3] : an[1];
        float gir0, gir1, giz0, giz1, gin0, gin1;
        bf2x2(gcur[0], gir0, gir1);
        bf2x2(gcur[1], giz0, giz1);
        bf2x2(gcur[2], gin0, gin1);
        const float rr0 = frcp(1.0f + fexp2(fmaf(S_RZ, grv0, gir0)));
        const float zz0 = frcp(1.0f + fexp2(fmaf(S_RZ, gzv0, giz0)));
        const float nn0 = fmaf(-2.0f, frcp(fexp2(fmaf(rr0 * S_N, gnv0, gin0)) + 1.0f), 1.0f);
        const float h0 = fmaf(zz0, hst0 - nn0, nn0);
        const float rr1 = frcp(1.0f + fexp2(fmaf(S_RZ, grv1, gir1)));
        const float zz1 = frcp(1.0f + fexp2(fmaf(S_RZ, gzv1, giz1)));
        const float nn1 = fmaf(-2.0f, frcp(fexp2(fmaf(rr1 * S_N, gnv1, gin1)) + 1.0f), 1.0f);
        const float h1 = fmaf(zz1, hst1 - nn1, nn1);
        hst0 = h0; hst1 = h1;
        const u32 hw2 = packbf(h0, h1);
        hbuf[cur ^ 1][(p * 2) * HS + ih]     = (u16)hw2;
        hbuf[cur ^ 1][(p * 2 + 1) * HS + ih] = (u16)(hw2 >> 16);
        hp[(size_t)t * 512] = hw2;
        gcur[0] = gnxt[0]; gcur[1] = gnxt[1]; gcur[2] = gnxt[2];
        gnxt[0] = g2s[0];  gnxt[1] = g2s[1];  gnxt[2] = g2s[2];
        ldsbar();
    }
}

// ---------------- K4: k_dot — LN2 + pos/neg dots, one wave per (grp8,t) ---------
// 3200 blocks x 256 threads. Lane (q,u): pair p=q (batches 2q,2q+1 of group),
// hidden slice i = u*8..u*8+7 (2x uint4 hseq2 loads, bf16x8 emb loads).
// Reductions over hidden = shfl_xor 1,2,4,8 within the 16-lane group.
__global__ __launch_bounds__(256) void k_dot(const int* __restrict__ seqs,
                                             const int* __restrict__ negs,
                                             const u32* __restrict__ hseq2,
                                             const u16* __restrict__ embT,
                                             const void* __restrict__ g2,
                                             const void* __restrict__ b2,
                                             void* __restrict__ out,
                                             const int* __restrict__ flag) {
    const int dt = *flag;
    const int wid = threadIdx.x >> 6;
    const int L = threadIdx.x & 63;
    const int q = L >> 4, u = L & 15;
    const int idx = blockIdx.x * 4 + wid;      // (grp8, t), 64*200 = 12800
    const int grp = idx / T_;
    const int t = idx - grp * T_;
    const int b0 = grp * 8 + q * 2;
    const u32* hc = hseq2 + ((size_t)(grp * T_ + t) * 4 + q) * 128 + u * 8;
    const uint4 ha = *(const uint4*)hc;
    const uint4 hb = *(const uint4*)(hc + 4);
    const u32 hv[8] = {ha.x, ha.y, ha.z, ha.w, hb.x, hb.y, hb.z, hb.w};
    float hlo[8], hhi[8];
    float s1a = 0.f, s2a = 0.f, s1b = 0.f, s2b = 0.f;
    #pragma unroll
    for (int j = 0; j < 8; j++) {
        float lo, hh; bf2x2(hv[j], lo, hh);
        hlo[j] = lo; hhi[j] = hh;
        s1a += lo; s2a += lo * lo;
        s1b += hh; s2b += hh * hh;
    }
    #pragma unroll
    for (int o = 1; o <= 8; o <<= 1) {
        s1a += __shfl_xor(s1a, o, 64); s2a += __shfl_xor(s2a, o, 64);
        s1b += __shfl_xor(s1b, o, 64); s2b += __shfl_xor(s2b, o, 64);
    }
    const float mua = s1a * (1.0f / H_);
    const float rsa = rsqrtf(s2a * (1.0f / H_) - mua * mua + 1e-8f);
    const float mub = s1b * (1.0f / H_);
    const float rsb = rsqrtf(s2b * (1.0f / H_) - mub * mub + 1e-8f);
    const int pt0 = seqs[b0 * L_ + t + 1],       nt0 = negs[b0 * L_ + t + 1];
    const int pt1 = seqs[(b0 + 1) * L_ + t + 1], nt1 = negs[(b0 + 1) * L_ + t + 1];
    const bf16x8 P0 = *(const bf16x8*)&embT[(size_t)pt0 * H_ + u * 8];
    const bf16x8 N0 = *(const bf16x8*)&embT[(size_t)nt0 * H_ + u * 8];
    const bf16x8 P1 = *(const bf16x8*)&embT[(size_t)pt1 * H_ + u * 8];
    const bf16x8 N1 = *(const bf16x8*)&embT[(size_t)nt1 * H_ + u * 8];
    float pe0 = 0.f, ne0 = 0.f, pe1 = 0.f, ne1 = 0.f;
    #pragma unroll
    for (int j = 0; j < 8; j++) {
        const float gvj = ldv(g2, dt, u * 8 + j);
        const float bvj = ldv(b2, dt, u * 8 + j);
        const float la = fmaf((hlo[j] - mua) * rsa, gvj, bvj);
        const float lb = fmaf((hhi[j] - mub) * rsb, gvj, bvj);
        pe0 = fmaf(la, bf2f((u16)P0[j]), pe0);
        ne0 = fmaf(la, bf2f((u16)N0[j]), ne0);
        pe1 = fmaf(lb, bf2f((u16)P1[j]), pe1);
        ne1 = fmaf(lb, bf2f((u16)N1[j]), ne1);
    }
    #pragma unroll
    for (int o = 1; o <= 8; o <<= 1) {
        pe0 += __shfl_xor(pe0, o, 64); ne0 += __shfl_xor(ne0, o, 64);
        pe1 += __shfl_xor(pe1, o, 64); ne1 += __shfl_xor(ne1, o, 64);
    }
    if (u == 0) {
        const int m0 = b0 * T_ + t;
        const int m1 = m0 + T_;
        if (dt) {
            ((float*)out)[m0] = pe0;      ((float*)out)[M_ + m0] = ne0;
            ((float*)out)[m1] = pe1;      ((float*)out)[M_ + m1] = ne1;
        } else {
            ((u16*)out)[m0] = f2bf(pe0);  ((u16*)out)[M_ + m0] = f2bf(ne0);
            ((u16*)out)[m1] = f2bf(pe1);  ((u16*)out)[M_ + m1] = f2bf(ne1);
        }
    }
}

extern "C" void kernel_launch(void* const* d_in, const int* in_sizes, int n_in,
                              void* d_out, int out_size, void* d_ws, size_t ws_size,
                              hipStream_t stream) {
    const int* seqs = (const int*)d_in[0];
    const int* negs = (const int*)d_in[1];
    const void* embW = d_in[2];
    const void* Wih  = d_in[3];
    const void* Whh  = d_in[4];
    const void* bih  = d_in[5];
    const void* bhh  = d_in[6];
    const void* g1   = d_in[7];
    const void* b1   = d_in[8];
    const void* g2   = d_in[9];
    const void* b2   = d_in[10];

    char* ws = (char*)d_ws;
    int* flag = (int*)ws;
    u16* embT  = (u16*)(ws + OFF_EMBT);
    u32* gi2   = (u32*)(ws + OFF_GI);
    u32* hseq2 = (u32*)(ws + OFF_HSEQ);

    k_sniff<<<1, 64, 0, stream>>>((const u32*)embW, flag);
    k_transpose<<<dim3((V_ + 31) / 32, H_ / 32), dim3(32, 32), 0, stream>>>(embW, embT, flag);
    k_gi<<<M_ / 64, 256, 0, stream>>>(seqs, embT, g1, b1, Wih, bih, bhh, gi2, flag);
    k_rec<<<NBLK8, 512, 0, stream>>>(gi2, Whh, bhh, hseq2, flag);
    k_dot<<<(B_ / 8) * T_ / 4, 256, 0, stream>>>(seqs, negs, hseq2, embT, g2, b2, d_out, flag);
}